// Round 8
// baseline (153.560 us; speedup 1.0000x reference)
//
#include <hip/hip_runtime.h>
#include <stdint.h>

typedef unsigned short u16;
typedef __attribute__((ext_vector_type(8))) short bf16x8;
typedef __attribute__((ext_vector_type(4))) float f32x4;
typedef __attribute__((ext_vector_type(16))) float f32x16;
typedef __attribute__((ext_vector_type(4))) unsigned short u16x4;
typedef __attribute__((ext_vector_type(4))) uint32_t u32x4;

__device__ __forceinline__ u16 f2bf(float f) {
  union { float f; uint32_t u; } c; c.f = f;
  uint32_t u = c.u;
  return (u16)((u + 0x7fffu + ((u >> 16) & 1u)) >> 16);
}

__device__ __forceinline__ uint32_t pk_bf16(float lo, float hi) {
  uint32_t d;
  asm("v_cvt_pk_bf16_f32 %0, %1, %2" : "=v"(d) : "v"(lo), "v"(hi));
  return d;
}

__device__ __forceinline__ void gload_lds16(const u16* g, u16* l) {
  __builtin_amdgcn_global_load_lds(
      (const __attribute__((address_space(1))) void*)g,
      (__attribute__((address_space(3))) void*)l, 16, 0, 0);
}

__global__ void cast_f32_bf16(const float* __restrict__ src, u16* __restrict__ dst, int n) {
  int i = (blockIdx.x * blockDim.x + threadIdx.x) * 4;
  int stride = gridDim.x * blockDim.x * 4;
  for (; i < n; i += stride) {
    float4 v = *reinterpret_cast<const float4*>(src + i);
    u16x4 o = { f2bf(v.x), f2bf(v.y), f2bf(v.z), f2bf(v.w) };
    *reinterpret_cast<u16x4*>(dst + i) = o;
  }
}

__global__ void cast_weights(const float* __restrict__ Wq, const float* __restrict__ Wk,
                             const float* __restrict__ Wv, const float* __restrict__ Wo,
                             u16* __restrict__ Wcat, u16* __restrict__ Wob) {
  int i = (blockIdx.x * blockDim.x + threadIdx.x) * 4;
  int stride = gridDim.x * blockDim.x * 4;
  for (; i < 4194304; i += stride) {
    const int sel = i >> 20;
    const int off = i & 1048575;
    const float* src = (sel == 0) ? Wq : (sel == 1) ? Wk : (sel == 2) ? Wv : Wo;
    float4 v = *reinterpret_cast<const float4*>(src + off);
    u16x4 o = { f2bf(v.x), f2bf(v.y), f2bf(v.z), f2bf(v.w) };
    u16* dst = (sel < 3) ? (Wcat + i) : (Wob + off);
    *reinterpret_cast<u16x4*>(dst) = o;
  }
}

// C = A @ B^T.  A[M][K], B[N][K] row-major bf16.  128x128 tile, BK=32.
#define QSCALE 0.18033688011112042f  /* 1/sqrt(64) * log2(e) */

template<int EPI>
__global__ __launch_bounds__(256) void gemm_bt(
    const u16* __restrict__ A, const u16* __restrict__ B,
    int M, int N, int K,
    u16* __restrict__ o0, u16* __restrict__ o1, u16* __restrict__ o2,
    float* __restrict__ fo, const float* __restrict__ bias)
{
  __shared__ __align__(16) u16 As[128 * 32];
  __shared__ __align__(16) u16 Bs[128 * 32];
  const int tid = threadIdx.x;
  const int w = tid >> 6, l = tid & 63;
  const int m0 = blockIdx.y * 128, n0 = blockIdx.x * 128;
  const int arow = (w << 4) + (l >> 2);
  const int acol = (l & 3) << 3;
  const int wr = (w >> 1) << 6, wc = (w & 1) << 6;
  const int lr = l & 15, hi = l >> 4;
  const int lk = hi << 3;
  f32x4 acc[4][4] = {};

  const u16* Ap = A + (size_t)(m0 + arow) * K + acol;
  const u16* Bp = B + (size_t)(n0 + arow) * K + acol;
  u16* asw = As + (w << 9);
  u16* bsw = Bs + (w << 9);

  for (int k0 = 0; k0 < K; k0 += 32) {
    gload_lds16(Ap + k0, asw);
    gload_lds16(Ap + (size_t)64 * K + k0, asw + 2048);
    gload_lds16(Bp + k0, bsw);
    gload_lds16(Bp + (size_t)64 * K + k0, bsw + 2048);
    __syncthreads();
    bf16x8 af[4], bfr[4];
#pragma unroll
    for (int m = 0; m < 4; ++m)
      af[m] = *(const bf16x8*)(As + (wr + m * 16 + lr) * 32 + lk);
#pragma unroll
    for (int n = 0; n < 4; ++n)
      bfr[n] = *(const bf16x8*)(Bs + (wc + n * 16 + lr) * 32 + lk);
    __builtin_amdgcn_s_setprio(1);
#pragma unroll
    for (int m = 0; m < 4; ++m)
#pragma unroll
      for (int n = 0; n < 4; ++n)
        acc[m][n] = __builtin_amdgcn_mfma_f32_16x16x32_bf16(af[m], bfr[n], acc[m][n], 0, 0, 0);
    __builtin_amdgcn_s_setprio(0);
    __syncthreads();
  }

#pragma unroll
  for (int mm = 0; mm < 4; ++mm) {
#pragma unroll
    for (int nn = 0; nn < 4; ++nn) {
      const int ng = n0 + wc + nn * 16 + lr;
      if (EPI == 0) {
        const int mat = ng >> 10;
        const int col = ng & 1023;
        const int h = col >> 6, dh = col & 63;
#pragma unroll
        for (int r = 0; r < 4; ++r) {
          const int mg = m0 + wr + mm * 16 + (hi << 2) + r;
          const int b = mg >> 11, s = mg & 2047;
          if (mat == 0)
            o0[(((size_t)(b * 16 + h)) * 2048 + s) * 64 + dh] = f2bf(acc[mm][nn][r] * QSCALE);
          else if (mat == 1)
            o1[(((size_t)(b * 16 + h)) * 2048 + s) * 64 + dh] = f2bf(acc[mm][nn][r]);
          else
            o2[(((size_t)(b * 16 + h)) * 64 + dh) * 2048 + s] = f2bf(acc[mm][nn][r]);
        }
      } else {
        const float bv = bias[ng];
#pragma unroll
        for (int r = 0; r < 4; ++r) {
          const int mg = m0 + wr + mm * 16 + (hi << 2) + r;
          fo[(size_t)mg * N + ng] = acc[mm][nn][r] + bv;
        }
      }
    }
  }
}

// Flash attention, causal, 32x32x16 MFMA.  Grid (32,32) snake-remapped,
// block 128 = 2 waves, each wave owns 32 q-rows (q = lane&31).
// S^T = mfma(K, Q): lane's 2x16 acc values all belong to its own q-col ->
// in-lane softmax (fixed-shift exp2).  P^T relayout to the PV B-operand is
// pure-register: 16x v_cvt_pk_bf16_f32 + 8x v_permlane32_swap_b32.
// O^T = mfma(V^T, P^T); normalizer is lane-local.  K/V 64-tile double-
// buffered via global_load_lds(16B) with pre-swizzled sources.
__global__ __launch_bounds__(128) void flash_attn(
    const u16* __restrict__ Qg, const u16* __restrict__ Kg,
    const u16* __restrict__ Vtg, u16* __restrict__ ctx)
{
  __shared__ __align__(16) u16 Ks[2][4096];
  __shared__ __align__(16) u16 Vts[2][4096];
  const int tid = threadIdx.x, wq = tid >> 6, l = tid & 63;
  const int lq = l & 31, hi5 = l >> 5;
  const int x = blockIdx.x, y = blockIdx.y;
  const int xi = (x + y) & 31;
  const int qt = (xi & 1) ? (31 - (xi >> 1)) : (xi >> 1);
  const int bh = y;
  const size_t kqbase = (size_t)bh * (2048 * 64);
  const int q0 = qt * 64;
  const int nkt = qt + 1;
  const int qg = q0 + wq * 32 + lq;   // lane's q-row

  // Q frags: qf[dblk] = Q[qg][dblk*16 + hi5*8 .. +7]  (pre-scaled by QSCALE)
  bf16x8 qf[4];
  {
    const u16* qp = Qg + kqbase + (size_t)qg * 64 + hi5 * 8;
    qf[0] = *(const bf16x8*)(qp);
    qf[1] = *(const bf16x8*)(qp + 16);
    qf[2] = *(const bf16x8*)(qp + 32);
    qf[3] = *(const bf16x8*)(qp + 48);
  }

  // staging: 512 16B-chunks per 64x64 tile, 4 K + 4 V per thread.
  // chunk c=(row,p): LDS linear dest, global source column pre-swizzled.
  const u16 *kgs0, *kgs1, *kgs2, *kgs3, *vgs0, *vgs1, *vgs2, *vgs3;
  u16 *kd0, *kd1, *kd2, *kd3, *vd0, *vd1, *vd2, *vd3;
  {
    const int c0 = tid, c1 = tid + 128, c2 = tid + 256, c3 = tid + 384;
#define SRCK(c) (Kg + kqbase + ((c) >> 3) * 64 + ((((c) & 7) ^ (((c) >> 3) & 7)) << 3))
#define SRCV(c) (Vtg + kqbase + ((c) >> 3) * 2048 + ((((c) & 7) ^ (((c) >> 3) & 7)) << 3))
    kgs0 = SRCK(c0); kgs1 = SRCK(c1); kgs2 = SRCK(c2); kgs3 = SRCK(c3);
    vgs0 = SRCV(c0); vgs1 = SRCV(c1); vgs2 = SRCV(c2); vgs3 = SRCV(c3);
#undef SRCK
#undef SRCV
    kd0 = &Ks[0][c0 * 8]; kd1 = &Ks[0][c1 * 8]; kd2 = &Ks[0][c2 * 8]; kd3 = &Ks[0][c3 * 8];
    vd0 = &Vts[0][c0 * 8]; vd1 = &Vts[0][c1 * 8]; vd2 = &Vts[0][c2 * 8]; vd3 = &Vts[0][c3 * 8];
  }

  f32x16 accO0 = {}, accO1 = {};
  float lsum = 0.0f;
  const int swz = (lq & 7) << 4;
  const int rb0 = (lq << 7);          // K/V row lq  byte base
  const int rb1 = rb0 + 4096;         // row lq+32

  // prologue: stage tile 0 into buf 0
  gload_lds16(kgs0, kd0); gload_lds16(kgs1, kd1);
  gload_lds16(kgs2, kd2); gload_lds16(kgs3, kd3);
  gload_lds16(vgs0, vd0); gload_lds16(vgs1, vd1);
  gload_lds16(vgs2, vd2); gload_lds16(vgs3, vd3);
  __syncthreads();

  int buf = 0;
  for (int kt = 0; kt < nkt; ++kt) {
    if (kt + 1 < nkt) {
      const int nb = (buf ^ 1) * 4096;
      const size_t ko = (size_t)(kt + 1) * 4096;
      const int vo = (kt + 1) * 64;
      gload_lds16(kgs0 + ko, kd0 + nb); gload_lds16(kgs1 + ko, kd1 + nb);
      gload_lds16(kgs2 + ko, kd2 + nb); gload_lds16(kgs3 + ko, kd3 + nb);
      gload_lds16(vgs0 + vo, vd0 + nb); gload_lds16(vgs1 + vo, vd1 + nb);
      gload_lds16(vgs2 + vo, vd2 + nb); gload_lds16(vgs3 + vo, vd3 + nb);
    }
    {
      const char* ksb = (const char*)&Ks[buf][0];
      const char* vsb = (const char*)&Vts[buf][0];
      // QK^T: s[h] = S^T rows h*32..h*32+31, col = lane's q
      f32x16 s0 = {}, s1 = {};
      __builtin_amdgcn_s_setprio(1);
#pragma unroll
      for (int dblk = 0; dblk < 4; ++dblk) {
        const int db = dblk * 32 + hi5 * 16;
        bf16x8 kf0 = *(const bf16x8*)(ksb + ((rb0 + db) ^ swz));
        bf16x8 kf1 = *(const bf16x8*)(ksb + ((rb1 + db) ^ swz));
        s0 = __builtin_amdgcn_mfma_f32_32x32x16_bf16(kf0, qf[dblk], s0, 0, 0, 0);
        s1 = __builtin_amdgcn_mfma_f32_32x32x16_bf16(kf1, qf[dblk], s1, 0, 0, 0);
      }
      __builtin_amdgcn_s_setprio(0);

      // softmax (in-lane): mask only on the diagonal tile, p = exp2(s)
      if (kt == nkt - 1) {
        const int thr = qg - kt * 64 - 4 * hi5;   // mask if h*32 + rowbase(r) > thr
#pragma unroll
        for (int r = 0; r < 16; ++r) {
          const int rl = (r & 3) + 8 * (r >> 2);
          if (rl > thr) s0[r] = -1e30f;
          if (rl + 32 > thr) s1[r] = -1e30f;
        }
      }
      float ts = 0.0f;
#pragma unroll
      for (int r = 0; r < 16; ++r) {
        s0[r] = exp2f(s0[r]);
        s1[r] = exp2f(s1[r]);
        ts += s0[r] + s1[r];
      }
      lsum += ts;

      // P^T relayout: C-layout -> B-frag via cvt_pk + permlane32_swap
      bf16x8 pf[2][2];
#pragma unroll
      for (int h = 0; h < 2; ++h) {
        const f32x16& sp = h ? s1 : s0;
#pragma unroll
        for (int kb = 0; kb < 2; ++kb) {
          const int b8 = kb * 8;
          uint32_t X = pk_bf16(sp[b8 + 0], sp[b8 + 1]);
          uint32_t Y = pk_bf16(sp[b8 + 4], sp[b8 + 5]);
          uint32_t Z = pk_bf16(sp[b8 + 2], sp[b8 + 3]);
          uint32_t W = pk_bf16(sp[b8 + 6], sp[b8 + 7]);
          asm volatile("v_permlane32_swap_b32 %0, %1" : "+v"(X), "+v"(Y));
          asm volatile("v_permlane32_swap_b32 %0, %1" : "+v"(Z), "+v"(W));
          union { u32x4 w; bf16x8 v; } u;
          u.w = (u32x4){ X, Z, Y, W };
          pf[h][kb] = u.v;
        }
      }

      // PV: O^T[dtile] += V^T @ P^T over 4 k-blocks of 16
      __builtin_amdgcn_s_setprio(1);
#pragma unroll
      for (int h = 0; h < 2; ++h)
#pragma unroll
        for (int kb = 0; kb < 2; ++kb) {
          const int kbyte = h * 64 + kb * 32 + hi5 * 16;
          bf16x8 vf0 = *(const bf16x8*)(vsb + ((rb0 + kbyte) ^ swz));
          bf16x8 vf1 = *(const bf16x8*)(vsb + ((rb1 + kbyte) ^ swz));
          accO0 = __builtin_amdgcn_mfma_f32_32x32x16_bf16(vf0, pf[h][kb], accO0, 0, 0, 0);
          accO1 = __builtin_amdgcn_mfma_f32_32x32x16_bf16(vf1, pf[h][kb], accO1, 0, 0, 0);
        }
      __builtin_amdgcn_s_setprio(0);
    }
    __syncthreads();
    buf ^= 1;
  }

  // epilogue: lane l and l^32 hold the two k-halves of the same q-row
  const float lt = lsum + __shfl_xor(lsum, 32);
  const float inv = 1.0f / lt;
  const int h = bh & 15, b = bh >> 4;
  const size_t rowbase = ((size_t)(b * 2048 + qg)) * 1024 + h * 64;
#pragma unroll
  for (int g = 0; g < 4; ++g) {
    const int d0 = 8 * g + 4 * hi5;
    u16x4 o0, o1;
#pragma unroll
    for (int r = 0; r < 4; ++r) {
      o0[r] = f2bf(accO0[4 * g + r] * inv);
      o1[r] = f2bf(accO1[4 * g + r] * inv);
    }
    *(u16x4*)(ctx + rowbase + d0) = o0;
    *(u16x4*)(ctx + rowbase + 32 + d0) = o1;
  }
}

extern "C" void kernel_launch(void* const* d_in, const int* in_sizes, int n_in,
                              void* d_out, int out_size, void* d_ws, size_t ws_size,
                              hipStream_t stream) {
  const float* x  = (const float*)d_in[0];
  const float* Wq = (const float*)d_in[1];
  const float* Wk = (const float*)d_in[2];
  const float* Wv = (const float*)d_in[3];
  const float* Wo = (const float*)d_in[4];
  const float* bo = (const float*)d_in[5];
  float* out = (float*)d_out;

  const size_t MB = 1ull << 20;
  if (ws_size < 48 * MB) return;  // loud failure instead of corruption
  char* ws = (char*)d_ws;
  u16* xb   = (u16*)(ws);             // [4096][1024]
  u16* Wcat = (u16*)(ws + 8 * MB);    // [3072][1024]  (Wq|Wk|Wv)
  u16* Wob  = (u16*)(ws + 14 * MB);   // [1024][1024]
  u16* Qb   = (u16*)(ws + 16 * MB);   // [B,H,S,DH]  (pre-scaled)
  u16* Kb   = (u16*)(ws + 24 * MB);   // [B,H,S,DH]
  u16* Vtb  = (u16*)(ws + 32 * MB);   // [B,H,DH,S]
  u16* ctxb = (u16*)(ws + 40 * MB);   // [4096][1024]

  hipLaunchKernelGGL(cast_f32_bf16, dim3(2048), dim3(256), 0, stream, x, xb, 4194304);
  hipLaunchKernelGGL(cast_weights, dim3(2048), dim3(256), 0, stream,
                     Wq, Wk, Wv, Wo, Wcat, Wob);

  hipLaunchKernelGGL((gemm_bt<0>), dim3(24, 32), dim3(256), 0, stream,
                     xb, Wcat, 4096, 3072, 1024, Qb, Kb, Vtb, (float*)nullptr, (const float*)nullptr);
  hipLaunchKernelGGL(flash_attn, dim3(32, 32), dim3(128), 0, stream, Qb, Kb, Vtb, ctxb);
  hipLaunchKernelGGL((gemm_bt<1>), dim3(8, 32), dim3(256), 0, stream,
                     ctxb, Wob, 4096, 1024, 1024,
                     (u16*)nullptr, (u16*)nullptr, (u16*)nullptr, out, bo);
}

// Round 9
// 141.985 us; speedup vs baseline: 1.0815x; 1.0815x over previous
//
#include <hip/hip_runtime.h>
#include <stdint.h>

typedef unsigned short u16;
typedef __attribute__((ext_vector_type(8))) short bf16x8;
typedef __attribute__((ext_vector_type(4))) float f32x4;
typedef __attribute__((ext_vector_type(4))) unsigned short u16x4;

__device__ __forceinline__ u16 f2bf(float f) {
  union { float f; uint32_t u; } c; c.f = f;
  uint32_t u = c.u;
  return (u16)((u + 0x7fffu + ((u >> 16) & 1u)) >> 16);
}

__device__ __forceinline__ uint32_t pk_bf16(float lo, float hi) {
  uint32_t d;
  asm("v_cvt_pk_bf16_f32 %0, %1, %2" : "=v"(d) : "v"(lo), "v"(hi));
  return d;
}

__device__ __forceinline__ void gload_lds16(const u16* g, u16* l) {
  __builtin_amdgcn_global_load_lds(
      (const __attribute__((address_space(1))) void*)g,
      (__attribute__((address_space(3))) void*)l, 16, 0, 0);
}

__global__ void cast_f32_bf16(const float* __restrict__ src, u16* __restrict__ dst, int n) {
  int i = (blockIdx.x * blockDim.x + threadIdx.x) * 4;
  int stride = gridDim.x * blockDim.x * 4;
  for (; i < n; i += stride) {
    float4 v = *reinterpret_cast<const float4*>(src + i);
    u16x4 o = { f2bf(v.x), f2bf(v.y), f2bf(v.z), f2bf(v.w) };
    *reinterpret_cast<u16x4*>(dst + i) = o;
  }
}

__global__ void cast_weights(const float* __restrict__ Wq, const float* __restrict__ Wk,
                             const float* __restrict__ Wv, const float* __restrict__ Wo,
                             u16* __restrict__ Wcat, u16* __restrict__ Wob) {
  int i = (blockIdx.x * blockDim.x + threadIdx.x) * 4;
  int stride = gridDim.x * blockDim.x * 4;
  for (; i < 4194304; i += stride) {
    const int sel = i >> 20;
    const int off = i & 1048575;
    const float* src = (sel == 0) ? Wq : (sel == 1) ? Wk : (sel == 2) ? Wv : Wo;
    float4 v = *reinterpret_cast<const float4*>(src + off);
    u16x4 o = { f2bf(v.x), f2bf(v.y), f2bf(v.z), f2bf(v.w) };
    u16* dst = (sel < 3) ? (Wcat + i) : (Wob + off);
    *reinterpret_cast<u16x4*>(dst) = o;
  }
}

// C = A @ B^T.  128x128 tile, BK=32, true LDS double-buffer with counted
// vmcnt + raw s_barrier (loads stay in flight across barriers; never
// drain to 0 in the main loop).
#define QSCALE 0.18033688011112042f  /* 1/sqrt(64) * log2(e) */

template<int EPI>
__global__ __launch_bounds__(256) void gemm_bt(
    const u16* __restrict__ A, const u16* __restrict__ B,
    int M, int N, int K,
    u16* __restrict__ o0, u16* __restrict__ o1, u16* __restrict__ o2,
    float* __restrict__ fo, const float* __restrict__ bias)
{
  __shared__ __align__(16) u16 As[2][128 * 32];
  __shared__ __align__(16) u16 Bs[2][128 * 32];
  const int tid = threadIdx.x;
  const int w = tid >> 6, l = tid & 63;
  const int m0 = blockIdx.y * 128, n0 = blockIdx.x * 128;
  const int arow = (w << 4) + (l >> 2);
  const int acol = (l & 3) << 3;
  const int wr = (w >> 1) << 6, wc = (w & 1) << 6;
  const int lr = l & 15, hi = l >> 4;
  const int lk = hi << 3;
  f32x4 acc[4][4] = {};

  const u16* Ap = A + (size_t)(m0 + arow) * K + acol;
  const u16* Bp = B + (size_t)(n0 + arow) * K + acol;
  const int so = (w << 9);

  // prologue: stage k0=0 into buf 0
  gload_lds16(Ap, &As[0][so]);
  gload_lds16(Ap + (size_t)64 * K, &As[0][so + 2048]);
  gload_lds16(Bp, &Bs[0][so]);
  gload_lds16(Bp + (size_t)64 * K, &Bs[0][so + 2048]);

  int buf = 0;
  for (int k0 = 0; k0 < K; k0 += 32) {
    if (k0 + 32 < K) {
      const int nb = buf ^ 1;
      gload_lds16(Ap + k0 + 32, &As[nb][so]);
      gload_lds16(Ap + (size_t)64 * K + k0 + 32, &As[nb][so + 2048]);
      gload_lds16(Bp + k0 + 32, &Bs[nb][so]);
      gload_lds16(Bp + (size_t)64 * K + k0 + 32, &Bs[nb][so + 2048]);
      asm volatile("s_waitcnt vmcnt(4)" ::: "memory");
    } else {
      asm volatile("s_waitcnt vmcnt(0)" ::: "memory");
    }
    __builtin_amdgcn_sched_barrier(0);
    __builtin_amdgcn_s_barrier();
    bf16x8 af[4], bfr[4];
#pragma unroll
    for (int m = 0; m < 4; ++m)
      af[m] = *(const bf16x8*)(&As[buf][0] + (wr + m * 16 + lr) * 32 + lk);
#pragma unroll
    for (int n = 0; n < 4; ++n)
      bfr[n] = *(const bf16x8*)(&Bs[buf][0] + (wc + n * 16 + lr) * 32 + lk);
    __builtin_amdgcn_s_setprio(1);
#pragma unroll
    for (int m = 0; m < 4; ++m)
#pragma unroll
      for (int n = 0; n < 4; ++n)
        acc[m][n] = __builtin_amdgcn_mfma_f32_16x16x32_bf16(af[m], bfr[n], acc[m][n], 0, 0, 0);
    __builtin_amdgcn_s_setprio(0);
    __builtin_amdgcn_s_barrier();
    buf ^= 1;
  }

#pragma unroll
  for (int mm = 0; mm < 4; ++mm) {
#pragma unroll
    for (int nn = 0; nn < 4; ++nn) {
      const int ng = n0 + wc + nn * 16 + lr;
      if (EPI == 0) {
        const int mat = ng >> 10;
        const int col = ng & 1023;
        const int h = col >> 6, dh = col & 63;
#pragma unroll
        for (int r = 0; r < 4; ++r) {
          const int mg = m0 + wr + mm * 16 + (hi << 2) + r;
          const int b = mg >> 11, s = mg & 2047;
          if (mat == 0)
            o0[(((size_t)(b * 16 + h)) * 2048 + s) * 64 + dh] = f2bf(acc[mm][nn][r] * QSCALE);
          else if (mat == 1)
            o1[(((size_t)(b * 16 + h)) * 2048 + s) * 64 + dh] = f2bf(acc[mm][nn][r]);
          else
            o2[(((size_t)(b * 16 + h)) * 64 + dh) * 2048 + s] = f2bf(acc[mm][nn][r]);
        }
      } else {
        const float bv = bias[ng];
#pragma unroll
        for (int r = 0; r < 4; ++r) {
          const int mg = m0 + wr + mm * 16 + (hi << 2) + r;
          fo[(size_t)mg * N + ng] = acc[mm][nn][r] + bv;
        }
      }
    }
  }
}

// Flash attention, causal (R7 16x16 structure + counted-vmcnt pipeline).
// Grid (32,32) snake-remapped, block 256 = 4 waves x 16 q-rows.
// KV tile 64 double-buffered; stage(t+1) issued, then vmcnt(8) (own
// stage(t) done) + raw barrier; loads for t+1 stay in flight across
// the whole compute of t.  Swapped QK^T -> in-lane exp2 softmax.
__global__ __launch_bounds__(256) void flash_attn(
    const u16* __restrict__ Qg, const u16* __restrict__ Kg,
    const u16* __restrict__ Vtg, u16* __restrict__ ctx)
{
  __shared__ __align__(16) u16 Ks[2][4096];
  __shared__ __align__(16) u16 Vts[2][4096];
  __shared__ __align__(16) u16 PT[4][1024];
  const int tid = threadIdx.x, w = tid >> 6, l = tid & 63;
  const int lr = l & 15, hi = l >> 4;
  const int x = blockIdx.x, y = blockIdx.y;
  const int xi = (x + y) & 31;
  const int qt = (xi & 1) ? (31 - (xi >> 1)) : (xi >> 1);
  const int bh = y;
  const size_t kqbase = (size_t)bh * (2048 * 64);
  const int q0 = qt * 64;
  const int nkt = qt + 1;

  bf16x8 qf[2];
  {
    const u16* qp = Qg + kqbase + (size_t)(q0 + w * 16 + lr) * 64 + hi * 8;
    qf[0] = *(const bf16x8*)(qp);
    qf[1] = *(const bf16x8*)(qp + 32);
  }

  const int c0 = (w * 2 + 0) * 64 + l;
  const int c1 = (w * 2 + 1) * 64 + l;
  const int r0 = c0 >> 3, p0 = c0 & 7;
  const int r1 = c1 >> 3, p1 = c1 & 7;
  const u16* kg0 = Kg + kqbase + r0 * 64 + ((p0 ^ (r0 & 7)) << 3);
  const u16* kg1 = Kg + kqbase + r1 * 64 + ((p1 ^ (r1 & 7)) << 3);
  const u16* vg0 = Vtg + kqbase + r0 * 2048 + ((p0 ^ (r0 & 7)) << 3);
  const u16* vg1 = Vtg + kqbase + r1 * 2048 + ((p1 ^ (r1 & 7)) << 3);
  u16* kd0 = (u16*)&Ks[0][(w * 2 + 0) * 512];
  u16* kd1 = (u16*)&Ks[0][(w * 2 + 1) * 512];
  u16* vd0 = (u16*)&Vts[0][(w * 2 + 0) * 512];
  u16* vd1 = (u16*)&Vts[0][(w * 2 + 1) * 512];

  f32x4 acc[4] = {};
  float lsum = 0.0f;
  const int qg = q0 + w * 16 + lr;

  // prologue: stage tile 0 into buf 0
  gload_lds16(kg0, kd0);
  gload_lds16(kg1, kd1);
  gload_lds16(vg0, vd0);
  gload_lds16(vg1, vd1);

  int buf = 0;
  for (int kt = 0; kt < nkt; ++kt) {
    if (kt + 1 < nkt) {
      const int nb = (buf ^ 1) * 4096;
      gload_lds16(kg0 + (size_t)(kt + 1) * 4096, kd0 + nb);
      gload_lds16(kg1 + (size_t)(kt + 1) * 4096, kd1 + nb);
      gload_lds16(vg0 + (kt + 1) * 64, vd0 + nb);
      gload_lds16(vg1 + (kt + 1) * 64, vd1 + nb);
      asm volatile("s_waitcnt vmcnt(8)" ::: "memory");
    } else {
      asm volatile("s_waitcnt vmcnt(0)" ::: "memory");
    }
    __builtin_amdgcn_sched_barrier(0);
    __builtin_amdgcn_s_barrier();
    {
      const u16* ksb = &Ks[buf][0];
      const u16* vsb = &Vts[buf][0];
      f32x4 sv[4];
      __builtin_amdgcn_s_setprio(1);
#pragma unroll
      for (int cf = 0; cf < 4; ++cf) {
        f32x4 z = {};
#pragma unroll
        for (int ch = 0; ch < 2; ++ch) {
          const int krow = cf * 16 + lr;
          const int boff = ((krow << 7) + ((ch * 32 + hi * 8) << 1)) ^ ((krow & 7) << 4);
          bf16x8 kf = *(const bf16x8*)((const char*)ksb + boff);
          z = __builtin_amdgcn_mfma_f32_16x16x32_bf16(kf, qf[ch], z, 0, 0, 0);
        }
        sv[cf] = z;
      }
      __builtin_amdgcn_s_setprio(0);

      const bool diag = (kt == nkt - 1);
      const int kb = kt * 64 + hi * 4;
      float ts = 0.0f;
#pragma unroll
      for (int cf = 0; cf < 4; ++cf) {
        f32x4 pv;
#pragma unroll
        for (int r = 0; r < 4; ++r) {
          float s = sv[cf][r];
          if (diag && (kb + cf * 16 + r) > qg) s = -1e30f;
          pv[r] = exp2f(s);
        }
        sv[cf] = pv;
        ts += (pv[0] + pv[1]) + (pv[2] + pv[3]);
      }
      lsum += ts;

      {
        const int rowb = lr << 7;
        const int swz = (lr & 7) << 4;
#pragma unroll
        for (int cf = 0; cf < 4; ++cf) {
          uint32_t d0 = pk_bf16(sv[cf][0], sv[cf][1]);
          uint32_t d1 = pk_bf16(sv[cf][2], sv[cf][3]);
          uint2 val = { d0, d1 };
          const int boff = (rowb + ((cf * 16 + hi * 4) << 1)) ^ swz;
          *(uint2*)((char*)&PT[w][0] + boff) = val;
        }
      }

#pragma unroll
      for (int ch = 0; ch < 2; ++ch) {
        const int boffp = ((lr << 7) + (ch * 64 + hi * 16)) ^ ((lr & 7) << 4);
        bf16x8 pa = *(const bf16x8*)((const char*)&PT[w][0] + boffp);
        __builtin_amdgcn_s_setprio(1);
#pragma unroll
        for (int df = 0; df < 4; ++df) {
          const int vrow = df * 16 + lr;
          const int boffv = ((vrow << 7) + ((ch * 32 + hi * 8) << 1)) ^ ((vrow & 7) << 4);
          bf16x8 vf = *(const bf16x8*)((const char*)vsb + boffv);
          acc[df] = __builtin_amdgcn_mfma_f32_16x16x32_bf16(pa, vf, acc[df], 0, 0, 0);
        }
        __builtin_amdgcn_s_setprio(0);
      }
    }
    __builtin_amdgcn_s_barrier();
    buf ^= 1;
  }

  float lf = lsum;
  lf += __shfl_xor(lf, 16);
  lf += __shfl_xor(lf, 32);
  const int h = bh & 15, b = bh >> 4;
#pragma unroll
  for (int r = 0; r < 4; ++r) {
    const float inv = 1.0f / __shfl(lf, hi * 4 + r);
    const int s = q0 + w * 16 + hi * 4 + r;
    const size_t rowbase = ((size_t)(b * 2048 + s)) * 1024 + h * 64;
#pragma unroll
    for (int df = 0; df < 4; ++df)
      ctx[rowbase + df * 16 + lr] = f2bf(acc[df][r] * inv);
  }
}

extern "C" void kernel_launch(void* const* d_in, const int* in_sizes, int n_in,
                              void* d_out, int out_size, void* d_ws, size_t ws_size,
                              hipStream_t stream) {
  const float* x  = (const float*)d_in[0];
  const float* Wq = (const float*)d_in[1];
  const float* Wk = (const float*)d_in[2];
  const float* Wv = (const float*)d_in[3];
  const float* Wo = (const float*)d_in[4];
  const float* bo = (const float*)d_in[5];
  float* out = (float*)d_out;

  const size_t MB = 1ull << 20;
  if (ws_size < 48 * MB) return;  // loud failure instead of corruption
  char* ws = (char*)d_ws;
  u16* xb   = (u16*)(ws);             // [4096][1024]
  u16* Wcat = (u16*)(ws + 8 * MB);    // [3072][1024]  (Wq|Wk|Wv)
  u16* Wob  = (u16*)(ws + 14 * MB);   // [1024][1024]
  u16* Qb   = (u16*)(ws + 16 * MB);   // [B,H,S,DH]  (pre-scaled)
  u16* Kb   = (u16*)(ws + 24 * MB);   // [B,H,S,DH]
  u16* Vtb  = (u16*)(ws + 32 * MB);   // [B,H,DH,S]
  u16* ctxb = (u16*)(ws + 40 * MB);   // [4096][1024]

  hipLaunchKernelGGL(cast_f32_bf16, dim3(2048), dim3(256), 0, stream, x, xb, 4194304);
  hipLaunchKernelGGL(cast_weights, dim3(2048), dim3(256), 0, stream,
                     Wq, Wk, Wv, Wo, Wcat, Wob);

  hipLaunchKernelGGL((gemm_bt<0>), dim3(24, 32), dim3(256), 0, stream,
                     xb, Wcat, 4096, 3072, 1024, Qb, Kb, Vtb, (float*)nullptr, (const float*)nullptr);
  hipLaunchKernelGGL(flash_attn, dim3(32, 32), dim3(256), 0, stream, Qb, Kb, Vtb, ctxb);
  hipLaunchKernelGGL((gemm_bt<1>), dim3(8, 32), dim3(256), 0, stream,
                     ctxb, Wob, 4096, 1024, 1024,
                     (u16*)nullptr, (u16*)nullptr, (u16*)nullptr, out, bo);
}